// Round 11
// baseline (117.048 us; speedup 1.0000x reference)
//
#include <hip/hip_runtime.h>

// Submanifold sparse 3D conv — v11: BARRIER-FREE. W staged per-lane in
// fragment order (prepass) -> 8 coalesced 1KB loads/item straight to regs;
// no LDS W, no s_barrier, waves fully independent. Unrolled 27-phase
// pipeline: rg(it+4) -> maps(it+3) -> srctab(it+2) -> gather(it+1) -> MFMA(it).
// srctab = per-wave LDS slot-inversion (3-slot rotation), lgkmcnt-only.
//
// Map identity (verified R1-R10): out[imap[m,p]] += feats[omap[m,p]] @ kernel[26-kk(m)]
// rg[m][tile] = lower_bound(imap[m], tile*32); fb row N = zeros.

#define CIN 64
#define COUT 64
#define TR 32
#define NOFF 26

typedef short bf16x8 __attribute__((ext_vector_type(8)));
typedef float f32x4 __attribute__((ext_vector_type(4)));

__device__ inline unsigned short bfbits(float f) {
    unsigned u = __builtin_bit_cast(unsigned, f);
    u += 0x7fffu + ((u >> 16) & 1u);          // RNE
    return (unsigned short)(u >> 16);
}

__device__ inline constexpr int kk_of_item(int i) {
    return (i >= 26) ? 13 : 26 - (i < 13 ? i : i + 1);
}

// ---------- fused prepass: feats->bf16 (+zero row), W frag-order, rg ------
// wf layout: wf[k][j][lane][8] ushorts, j=ot*2+h:
//   value = W_bf16[k][c = h*32 + (lane>>4)*8 + e][o = (j>>1)*16 + (lane&15)]
__global__ __launch_bounds__(256) void prep_all(
    const float* __restrict__ feats, unsigned short* __restrict__ fb,
    const float* __restrict__ W, unsigned short* __restrict__ wf,
    const int* __restrict__ imap, int* __restrict__ rg,
    int N, int P, int nt, int FB)
{
    const int bid = blockIdx.x, tid = threadIdx.x;
    if (bid < FB) {
        const int i8 = (bid * 256 + tid) * 8;
        const int nf = N * 64;
        if (i8 >= (N + 1) * 64) return;
        union { unsigned short u[8]; bf16x8 v; } r;
        if (i8 >= nf) {
            r.v = (bf16x8)0;
        } else {
            const float4 v0 = *(const float4*)(feats + i8);
            const float4 v1 = *(const float4*)(feats + i8 + 4);
            r.u[0] = bfbits(v0.x); r.u[1] = bfbits(v0.y);
            r.u[2] = bfbits(v0.z); r.u[3] = bfbits(v0.w);
            r.u[4] = bfbits(v1.x); r.u[5] = bfbits(v1.y);
            r.u[6] = bfbits(v1.z); r.u[7] = bfbits(v1.w);
        }
        *(bf16x8*)(fb + i8) = r.v;
    } else if (bid < FB + 27) {
        const int k = bid - FB;
        for (int idx = tid; idx < CIN * COUT; idx += 256) {
            const int j = idx >> 9, l = (idx >> 3) & 63, e = idx & 7;
            const int o = (j >> 1) * 16 + (l & 15);
            const int c = (j & 1) * 32 + (l >> 4) * 8 + e;
            wf[k * 4096 + idx] = bfbits(W[(k * 64 + c) * 64 + o]);
        }
    } else {
        const int idx = (bid - FB - 27) * 256 + tid;
        const int nt1 = nt + 1;
        if (idx >= NOFF * nt1) return;
        const int m = idx / nt1, tile = idx % nt1;
        const int* a = imap + (size_t)m * P;
        const int target = tile * TR;
        int lo = 0, hi = P;
        while (lo < hi) {
            const int mid = (lo + hi) >> 1;
            const int v = a[mid];
            const int key = (v < 0) ? 0x7fffffff : v;
            if (key < target) lo = mid + 1; else hi = mid;
        }
        rg[(size_t)m * nt1 + tile] = lo;
    }
}

// ---------- main ----------------------------------------------------------
__global__ __launch_bounds__(256, 4) void spconv_v11(
    const unsigned short* __restrict__ fb,   // feats bf16 [N+1][64], row N = 0
    const unsigned short* __restrict__ wf,   // [27][8][64][8] frag-order bf16
    const int* __restrict__ imap, const int* __restrict__ omap,
    const int* __restrict__ rg,              // [26][nt+1]
    float* __restrict__ out, int N, int P, int nt, int nwg)
{
    __shared__ int srctab[4][3][32];         // per-wave, 3-slot rotation

    const int tid = threadIdx.x, w = tid >> 6, lane = tid & 63;
    const int col = lane & 15, grp = lane >> 4;

    // bijective XCD swizzle (m204)
    const int orig = blockIdx.x;
    const int q = nwg >> 3, r8 = nwg & 7;
    const int xcd = orig & 7, kb = orig >> 3;
    const int sb = (xcd < r8 ? xcd * (q + 1) : r8 * (q + 1) + (xcd - r8) * q) + kb;

    const int t = sb * 4 + w;                // this wave's 32-row tile
    const int tt = (t < nt) ? t : (nt - 1);
    const int r0 = t * TR;
    const int nt1 = nt + 1;

    int p0a[27], cnta[27];
    int mva[27];
    bf16x8 af[27][2][2];                     // gather window ~2

    auto RGLOAD = [&](int j) {
        const int* rp = rg + (size_t)j * nt1 + tt;
        p0a[j] = rp[0];
        cnta[j] = rp[1];
    };
    auto MAPS = [&](int j) {
        const int p0 = p0a[j];
        const int cnt = cnta[j] - p0;        // <= 32 guaranteed
        cnta[j] = cnt;
        int idx = p0 + ((lane < cnt) ? lane : 0);
        idx = (idx < P) ? idx : P - 1;
        const int iv = imap[(size_t)j * P + idx];
        const int ov = omap[(size_t)j * P + idx];
        mva[j] = (ov << 6) | ((iv - r0) & 63);
    };
    auto STWRITE = [&](int j) {              // reset then scatter (same-wave order)
        int* st = srctab[w][j % 3];
        if (lane < 32) st[lane] = N;
        if (lane < cnta[j]) st[mva[j] & 63] = mva[j] >> 6;
    };
    auto READGATHER = [&](int j) {
        int s0, s1;
        if (j < 26) {
            const int* st = srctab[w][j % 3];
            s0 = st[col];
            s1 = st[col + 16];
        } else {
            const int ra = r0 + col, rb = r0 + 16 + col;
            s0 = (ra < N) ? ra : N;
            s1 = (rb < N) ? rb : N;
        }
        const bf16x8* fp = (const bf16x8*)(fb + (size_t)s0 * 64 + grp * 8);
        af[j][0][0] = fp[0];
        af[j][0][1] = fp[4];
        const bf16x8* fq = (const bf16x8*)(fb + (size_t)s1 * 64 + grp * 8);
        af[j][1][0] = fq[0];
        af[j][1][1] = fq[4];
    };

    // --- prologue ---
#pragma unroll
    for (int j = 0; j < 4; ++j) RGLOAD(j);
#pragma unroll
    for (int j = 0; j < 3; ++j) MAPS(j);
    STWRITE(0); STWRITE(1);
    READGATHER(0);

    f32x4 acc[2][4];
#pragma unroll
    for (int s = 0; s < 2; ++s)
#pragma unroll
        for (int ot = 0; ot < 4; ++ot) acc[s][ot] = {0.f, 0.f, 0.f, 0.f};

    // --- 27 fully-unrolled phases, no barriers ---
#pragma unroll
    for (int it = 0; it < 27; ++it) {
        if (it + 4 < 26) RGLOAD(it + 4);
        if (it + 3 < 26) MAPS(it + 3);
        if (it + 2 < 26) STWRITE(it + 2);

        // current item's W fragments: 8 coalesced 1KB loads (L1/L2-hot)
        bf16x8 frw[8];
        {
            const unsigned short* wk = wf + kk_of_item(it) * 4096;
#pragma unroll
            for (int j = 0; j < 8; ++j)
                frw[j] = *(const bf16x8*)(wk + j * 512 + lane * 8);
        }

        if (it + 1 <= 26) READGATHER(it + 1);

        __builtin_amdgcn_s_setprio(1);
#pragma unroll
        for (int ot = 0; ot < 4; ++ot) {
#pragma unroll
            for (int s = 0; s < 2; ++s) {
                acc[s][ot] = __builtin_amdgcn_mfma_f32_16x16x32_bf16(af[it][s][0], frw[ot * 2 + 0], acc[s][ot], 0, 0, 0);
                acc[s][ot] = __builtin_amdgcn_mfma_f32_16x16x32_bf16(af[it][s][1], frw[ot * 2 + 1], acc[s][ot], 0, 0, 0);
            }
        }
        __builtin_amdgcn_s_setprio(0);
    }

    // --- write-out ---
#pragma unroll
    for (int s = 0; s < 2; ++s)
#pragma unroll
        for (int ot = 0; ot < 4; ++ot) {
            const f32x4 cv = acc[s][ot];
#pragma unroll
            for (int reg = 0; reg < 4; ++reg) {
                const int rr = r0 + s * 16 + grp * 4 + reg;
                if (rr < N) out[(size_t)rr * 64 + ot * 16 + col] = cv[reg];
            }
        }
}

// ---------- fallback (fp32 + atomics, round-0) ----------------------------
template <int MODE>
__global__ __launch_bounds__(256) void spconv_fb(
    const float* __restrict__ feats, const float* __restrict__ W,
    const int* __restrict__ imap, const int* __restrict__ omap,
    float* __restrict__ out, int npairs)
{
    __shared__ float4 wt4[16 * 64];
    const int tid = threadIdx.x, koff = blockIdx.y;
    const float* Wk;
    const int* im = nullptr; const int* om = nullptr;
    if (MODE == 0) Wk = W + 13 * (CIN * COUT);
    else {
        const int kk = (koff < 13) ? koff : koff + 1;
        Wk = W + (size_t)kk * (CIN * COUT);
        im = imap + (size_t)koff * npairs; om = omap + (size_t)koff * npairs;
    }
    float* wts = (float*)wt4;
    for (int idx = tid; idx < CIN * COUT; idx += 256) {
        const int c = idx >> 6, o = idx & 63;
        wts[((c >> 2) * 64 + o) * 4 + (c & 3)] = Wk[idx];
    }
    __syncthreads();
    const int o = tid & 63, w = tid >> 6;
    const int base = blockIdx.x * 256 + w * 64;
    const float4* f4p = (const float4*)feats;
    for (int n = 0; n < 64; ++n) {
        const int p = base + n;
        if (p >= npairs) break;
        int i, j;
        if (MODE == 0) { i = p; j = p; }
        else { i = im[p]; if (i < 0) continue; j = om[p]; }
        i = __builtin_amdgcn_readfirstlane(i);
        float a = 0.f;
#pragma unroll
        for (int c4 = 0; c4 < 16; ++c4) {
            const float4 f = f4p[(size_t)i * 16 + c4];
            const float4 wv = wt4[c4 * 64 + o];
            a += f.x * wv.x + f.y * wv.y + f.z * wv.z + f.w * wv.w;
        }
        if (MODE == 0) out[(size_t)j * COUT + o] = a;
        else atomicAdd(&out[(size_t)j * COUT + o], a);
    }
}

extern "C" void kernel_launch(void* const* d_in, const int* in_sizes, int n_in,
                              void* d_out, int out_size, void* d_ws, size_t ws_size,
                              hipStream_t stream) {
    const float* feats = (const float*)d_in[0];
    const float* W     = (const float*)d_in[1];
    const int* imap    = (const int*)d_in[2];
    const int* omap    = (const int*)d_in[3];
    float* out         = (float*)d_out;

    const int N = in_sizes[0] / CIN;
    const int P = in_sizes[2] / NOFF;
    const int nt = (N + TR - 1) / TR;                       // 6250
    const int nt1 = nt + 1;

    const size_t fb_bytes = (size_t)(N + 1) * 64 * sizeof(unsigned short);
    const size_t wf_bytes = 27 * 64 * 64 * sizeof(unsigned short);
    const size_t rg_bytes = (size_t)NOFF * nt1 * sizeof(int);

    if (ws_size < fb_bytes + wf_bytes + rg_bytes) {
        dim3 blk(256);
        dim3 gc((N + 255) / 256, 1);
        spconv_fb<0><<<gc, blk, 0, stream>>>(feats, W, nullptr, nullptr, out, N);
        dim3 go((P + 255) / 256, NOFF);
        spconv_fb<1><<<go, blk, 0, stream>>>(feats, W, imap, omap, out, P);
        return;
    }

    unsigned short* fbp = (unsigned short*)d_ws;
    unsigned short* wf  = (unsigned short*)((char*)d_ws + fb_bytes);
    int* rg             = (int*)((char*)d_ws + fb_bytes + wf_bytes);

    const int FB  = ((N + 1) * 64 + 2047) / 2048;
    const int RGB = (NOFF * nt1 + 255) / 256;
    prep_all<<<FB + 27 + RGB, 256, 0, stream>>>(feats, fbp, W, wf, imap, rg,
                                                N, P, nt, FB);

    const int nwg = (nt + 3) / 4;                           // 1563
    spconv_v11<<<nwg, 256, 0, stream>>>(fbp, wf, imap, omap, rg, out,
                                        N, P, nt, nwg);
}

// Round 12
// 87.852 us; speedup vs baseline: 1.3323x; 1.3323x over previous
//
#include <hip/hip_runtime.h>

// Submanifold sparse 3D conv — v12: v10 body + 4-slot W LDS rotation with a
// barrier only every 2nd phase (13 rendezvous instead of 26).
// W pipeline: phase it loads wr[it+3] (global->regs), ds_writes wr[it+2] into
// slot (it+2)%4; barrier after odd phases publishes two slots at once.
// Between barriers: reads hit slots {2k,2k+1}%4, writes hit {2k+2,2k+3}%4 —
// disjoint, so waves may drift a full phase without racing.
// srctab (per-wave, private) and gather pipeline unchanged from v10.
//
// Map identity (verified R1-R11): out[imap[m,p]] += feats[omap[m,p]] @ kernel[26-kk(m)]
// rg[m][tile] = lower_bound(imap[m], tile*32); fb row N = zeros.

#define CIN 64
#define COUT 64
#define TR 32
#define NOFF 26

typedef short bf16x8 __attribute__((ext_vector_type(8)));
typedef unsigned short ushort8 __attribute__((ext_vector_type(8)));
typedef float f32x4 __attribute__((ext_vector_type(4)));

__device__ inline unsigned short bfbits(float f) {
    unsigned u = __builtin_bit_cast(unsigned, f);
    u += 0x7fffu + ((u >> 16) & 1u);          // RNE
    return (unsigned short)(u >> 16);
}

__device__ inline constexpr int kk_of_item(int i) {
    return (i >= 26) ? 13 : 26 - (i < 13 ? i : i + 1);
}

// ---------- fused prepass: feats->bf16 (+zero row), W swizzle, rg search ---
__global__ __launch_bounds__(256) void prep_all(
    const float* __restrict__ feats, unsigned short* __restrict__ fb,
    const float* __restrict__ W, unsigned short* __restrict__ Wt,
    const int* __restrict__ imap, int* __restrict__ rg,
    int N, int P, int nt, int FB)
{
    const int bid = blockIdx.x, tid = threadIdx.x;
    if (bid < FB) {
        const int i8 = (bid * 256 + tid) * 8;
        const int nf = N * 64;
        if (i8 >= (N + 1) * 64) return;
        union { unsigned short u[8]; bf16x8 v; } r;
        if (i8 >= nf) {
            r.v = (bf16x8)0;
        } else {
            const float4 v0 = *(const float4*)(feats + i8);
            const float4 v1 = *(const float4*)(feats + i8 + 4);
            r.u[0] = bfbits(v0.x); r.u[1] = bfbits(v0.y);
            r.u[2] = bfbits(v0.z); r.u[3] = bfbits(v0.w);
            r.u[4] = bfbits(v1.x); r.u[5] = bfbits(v1.y);
            r.u[6] = bfbits(v1.z); r.u[7] = bfbits(v1.w);
        }
        *(bf16x8*)(fb + i8) = r.v;
    } else if (bid < FB + 27) {
        // W [27][c][o] -> Wt [27][o][c] bf16, pre-swizzled (16B unit q ^= o&7)
        const int k = bid - FB;
        for (int idx = tid; idx < CIN * COUT; idx += 256) {
            const int c = idx >> 6, o = idx & 63;
            const int q = c >> 3, e = c & 7;
            Wt[((k * 64 + o) * 64) + (((q ^ (o & 7)) << 3) + e)] =
                bfbits(W[(k * 64 + c) * 64 + o]);
        }
    } else {
        const int idx = (bid - FB - 27) * 256 + tid;
        const int nt1 = nt + 1;
        if (idx >= NOFF * nt1) return;
        const int m = idx / nt1, tile = idx % nt1;
        const int* a = imap + (size_t)m * P;
        const int target = tile * TR;
        int lo = 0, hi = P;
        while (lo < hi) {
            const int mid = (lo + hi) >> 1;
            const int v = a[mid];
            const int key = (v < 0) ? 0x7fffffff : v;
            if (key < target) lo = mid + 1; else hi = mid;
        }
        rg[(size_t)m * nt1 + tile] = lo;
    }
}

// ---------- main ----------------------------------------------------------
__global__ __launch_bounds__(256, 4) void spconv_v12(
    const unsigned short* __restrict__ fb,   // feats bf16 [N+1][64], row N = 0
    const unsigned short* __restrict__ wt,   // [27][64][64] bf16, pre-swizzled
    const int* __restrict__ imap, const int* __restrict__ omap,
    const int* __restrict__ rg,              // [26][nt+1]
    float* __restrict__ out, int N, int P, int nt, int nwg)
{
    __shared__ unsigned short wbuf[4][4096]; // 4 x 8KB W rotation
    __shared__ int srctab[4][3][32];         // per-wave, 3-slot rotation

    const int tid = threadIdx.x, w = tid >> 6, lane = tid & 63;
    const int col = lane & 15, grp = lane >> 4;

    // bijective XCD swizzle (m204)
    const int orig = blockIdx.x;
    const int q = nwg >> 3, r8 = nwg & 7;
    const int xcd = orig & 7, kb = orig >> 3;
    const int sb = (xcd < r8 ? xcd * (q + 1) : r8 * (q + 1) + (xcd - r8) * q) + kb;

    const int t = sb * 4 + w;                // this wave's 32-row tile
    const int tt = (t < nt) ? t : (nt - 1);
    const int r0 = t * TR;
    const int nt1 = nt + 1;

    // pipeline state — statically indexed (full unroll => rolling registers)
    int p0a[27], cnta[27];
    int mva[27];
    bf16x8 af[27][2][2];
    ushort8 wr[27][2];

    auto RGLOAD = [&](int j) {
        const int* rp = rg + (size_t)j * nt1 + tt;
        p0a[j] = rp[0];
        cnta[j] = rp[1];
    };
    auto MAPS = [&](int j) {
        const int p0 = p0a[j];
        const int cnt = cnta[j] - p0;        // <= 32 guaranteed
        cnta[j] = cnt;
        int idx = p0 + ((lane < cnt) ? lane : 0);
        idx = (idx < P) ? idx : P - 1;
        const int iv = imap[(size_t)j * P + idx];
        const int ov = omap[(size_t)j * P + idx];
        mva[j] = (ov << 6) | ((iv - r0) & 63);
    };
    auto STWRITE = [&](int j) {              // reset then scatter (same-wave order)
        int* st = srctab[w][j % 3];
        if (lane < 32) st[lane] = N;
        if (lane < cnta[j]) st[mva[j] & 63] = mva[j] >> 6;
    };
    auto READGATHER = [&](int j) {
        int s0, s1;
        if (j < 26) {
            const int* st = srctab[w][j % 3];
            s0 = st[col];
            s1 = st[col + 16];
        } else {
            const int ra = r0 + col, rb = r0 + 16 + col;
            s0 = (ra < N) ? ra : N;
            s1 = (rb < N) ? rb : N;
        }
        const bf16x8* fp = (const bf16x8*)(fb + (size_t)s0 * 64 + grp * 8);
        af[j][0][0] = fp[0];
        af[j][0][1] = fp[4];
        const bf16x8* fq = (const bf16x8*)(fb + (size_t)s1 * 64 + grp * 8);
        af[j][1][0] = fq[0];
        af[j][1][1] = fq[4];
    };

    // --- prologue ---
#pragma unroll
    for (int j = 0; j < 4; ++j) if (j < 26) RGLOAD(j);
#pragma unroll
    for (int j = 0; j < 3; ++j) if (j < 26) MAPS(j);
    STWRITE(0); STWRITE(1);

    {   // W0 -> slot0, W1 -> slot1 via temp regs; W2 -> wr[2]
        const unsigned short* wk0 = wt + kk_of_item(0) * 4096;
        const ushort8 t0 = *(const ushort8*)(wk0 + tid * 8);
        const ushort8 t1 = *(const ushort8*)(wk0 + 2048 + tid * 8);
        const unsigned short* wk1 = wt + kk_of_item(1) * 4096;
        const ushort8 t2 = *(const ushort8*)(wk1 + tid * 8);
        const ushort8 t3 = *(const ushort8*)(wk1 + 2048 + tid * 8);
        const unsigned short* wk2 = wt + kk_of_item(2) * 4096;
        wr[2][0] = *(const ushort8*)(wk2 + tid * 8);
        wr[2][1] = *(const ushort8*)(wk2 + 2048 + tid * 8);
        *(ushort8*)(&wbuf[0][tid * 8]) = t0;
        *(ushort8*)(&wbuf[0][2048 + tid * 8]) = t1;
        *(ushort8*)(&wbuf[1][tid * 8]) = t2;
        *(ushort8*)(&wbuf[1][2048 + tid * 8]) = t3;
    }
    READGATHER(0);
    asm volatile("s_waitcnt lgkmcnt(0)" ::: "memory");
    __builtin_amdgcn_s_barrier();

    f32x4 acc[2][4];
#pragma unroll
    for (int s = 0; s < 2; ++s)
#pragma unroll
        for (int ot = 0; ot < 4; ++ot) acc[s][ot] = {0.f, 0.f, 0.f, 0.f};

    // --- 27 fully-unrolled phases, barrier every 2nd ---
#pragma unroll
    for (int it = 0; it < 27; ++it) {
        if (it + 4 < 26) RGLOAD(it + 4);
        if (it + 3 < 26) MAPS(it + 3);
        if (it + 2 < 26) STWRITE(it + 2);
        if (it + 1 <= 26) READGATHER(it + 1);
        // W pipeline: load (it+3) -> regs; ds_write (it+2) from phase-old regs
        if (it + 3 <= 26) {
            const unsigned short* wk = wt + kk_of_item(it + 3) * 4096;
            wr[it + 3][0] = *(const ushort8*)(wk + tid * 8);
            wr[it + 3][1] = *(const ushort8*)(wk + 2048 + tid * 8);
        }
        if (it + 2 <= 26) {
            unsigned short* nb = wbuf[(it + 2) & 3];
            *(ushort8*)(&nb[tid * 8]) = wr[it + 2][0];
            *(ushort8*)(&nb[2048 + tid * 8]) = wr[it + 2][1];
        }
        // compute item it: 8 swizzled ds_read_b128 + 16 MFMA
        const unsigned short* cb = wbuf[it & 3];
        __builtin_amdgcn_s_setprio(1);
#pragma unroll
        for (int ot = 0; ot < 4; ++ot) {
            const int o = ot * 16 + col;
            const bf16x8 b0 = *(const bf16x8*)(cb + o * 64 + ((grp ^ (col & 7)) << 3));
            const bf16x8 b1 = *(const bf16x8*)(cb + o * 64 + (((4 + grp) ^ (col & 7)) << 3));
#pragma unroll
            for (int s = 0; s < 2; ++s) {
                acc[s][ot] = __builtin_amdgcn_mfma_f32_16x16x32_bf16(af[it][s][0], b0, acc[s][ot], 0, 0, 0);
                acc[s][ot] = __builtin_amdgcn_mfma_f32_16x16x32_bf16(af[it][s][1], b1, acc[s][ot], 0, 0, 0);
            }
        }
        __builtin_amdgcn_s_setprio(0);
        // barrier only after odd phases: publishes the two slots staged in
        // this window; reads/writes between barriers are slot-disjoint.
        if ((it & 1) == 1 && it < 26) {
            asm volatile("s_waitcnt lgkmcnt(0)" ::: "memory");
            __builtin_amdgcn_s_barrier();
        }
    }

    // --- write-out ---
#pragma unroll
    for (int s = 0; s < 2; ++s)
#pragma unroll
        for (int ot = 0; ot < 4; ++ot) {
            const f32x4 cv = acc[s][ot];
#pragma unroll
            for (int reg = 0; reg < 4; ++reg) {
                const int rr = r0 + s * 16 + grp * 4 + reg;
                if (rr < N) out[(size_t)rr * 64 + ot * 16 + col] = cv[reg];
            }
        }
}

// ---------- fallback (fp32 + atomics, round-0) ----------------------------
template <int MODE>
__global__ __launch_bounds__(256) void spconv_fb(
    const float* __restrict__ feats, const float* __restrict__ W,
    const int* __restrict__ imap, const int* __restrict__ omap,
    float* __restrict__ out, int npairs)
{
    __shared__ float4 wt4[16 * 64];
    const int tid = threadIdx.x, koff = blockIdx.y;
    const float* Wk;
    const int* im = nullptr; const int* om = nullptr;
    if (MODE == 0) Wk = W + 13 * (CIN * COUT);
    else {
        const int kk = (koff < 13) ? koff : koff + 1;
        Wk = W + (size_t)kk * (CIN * COUT);
        im = imap + (size_t)koff * npairs; om = omap + (size_t)koff * npairs;
    }
    float* wts = (float*)wt4;
    for (int idx = tid; idx < CIN * COUT; idx += 256) {
        const int c = idx >> 6, o = idx & 63;
        wts[((c >> 2) * 64 + o) * 4 + (c & 3)] = Wk[idx];
    }
    __syncthreads();
    const int o = tid & 63, w = tid >> 6;
    const int base = blockIdx.x * 256 + w * 64;
    const float4* f4p = (const float4*)feats;
    for (int n = 0; n < 64; ++n) {
        const int p = base + n;
        if (p >= npairs) break;
        int i, j;
        if (MODE == 0) { i = p; j = p; }
        else { i = im[p]; if (i < 0) continue; j = om[p]; }
        i = __builtin_amdgcn_readfirstlane(i);
        float a = 0.f;
#pragma unroll
        for (int c4 = 0; c4 < 16; ++c4) {
            const float4 f = f4p[(size_t)i * 16 + c4];
            const float4 wv = wt4[c4 * 64 + o];
            a += f.x * wv.x + f.y * wv.y + f.z * wv.z + f.w * wv.w;
        }
        if (MODE == 0) out[(size_t)j * COUT + o] = a;
        else atomicAdd(&out[(size_t)j * COUT + o], a);
    }
}

extern "C" void kernel_launch(void* const* d_in, const int* in_sizes, int n_in,
                              void* d_out, int out_size, void* d_ws, size_t ws_size,
                              hipStream_t stream) {
    const float* feats = (const float*)d_in[0];
    const float* W     = (const float*)d_in[1];
    const int* imap    = (const int*)d_in[2];
    const int* omap    = (const int*)d_in[3];
    float* out         = (float*)d_out;

    const int N = in_sizes[0] / CIN;
    const int P = in_sizes[2] / NOFF;
    const int nt = (N + TR - 1) / TR;                       // 6250
    const int nt1 = nt + 1;

    const size_t fb_bytes = (size_t)(N + 1) * 64 * sizeof(unsigned short);
    const size_t wt_bytes = 27 * 64 * 64 * sizeof(unsigned short);
    const size_t rg_bytes = (size_t)NOFF * nt1 * sizeof(int);

    if (ws_size < fb_bytes + wt_bytes + rg_bytes) {
        dim3 blk(256);
        dim3 gc((N + 255) / 256, 1);
        spconv_fb<0><<<gc, blk, 0, stream>>>(feats, W, nullptr, nullptr, out, N);
        dim3 go((P + 255) / 256, NOFF);
        spconv_fb<1><<<go, blk, 0, stream>>>(feats, W, imap, omap, out, P);
        return;
    }

    unsigned short* fbp = (unsigned short*)d_ws;
    unsigned short* Wt  = (unsigned short*)((char*)d_ws + fb_bytes);
    int* rg             = (int*)((char*)d_ws + fb_bytes + wt_bytes);

    const int FB  = ((N + 1) * 64 + 2047) / 2048;
    const int RGB = (NOFF * nt1 + 255) / 256;
    prep_all<<<FB + 27 + RGB, 256, 0, stream>>>(feats, fbp, W, Wt, imap, rg,
                                                N, P, nt, FB);

    const int nwg = (nt + 3) / 4;                           // 1563
    spconv_v12<<<nwg, 256, 0, stream>>>(fbp, Wt, imap, omap, rg, out,
                                        N, P, nt, nwg);
}